// Round 2
// baseline (2367.822 us; speedup 1.0000x reference)
//
#include <hip/hip_runtime.h>
#include <hip/hip_bf16.h>

#define V_NODES 100000
#define DD 64

__device__ __forceinline__ float waveAllSum(float v) {
#pragma unroll
    for (int o = 32; o > 0; o >>= 1) v += __shfl_xor(v, o, 64);
    return v;
}

// Per-node attention scores for both GATs: e = tanh(N @ W1) @ w2
__global__ __launch_bounds__(256) void score_kernel(
    const float* __restrict__ lN, const float* __restrict__ gN,
    const float* __restrict__ lW1, const float* __restrict__ lw2,
    const float* __restrict__ gW1, const float* __restrict__ gw2,
    float* __restrict__ eL, float* __restrict__ eG)
{
    __shared__ float sLW1[4096];
    __shared__ float sGW1[4096];
    __shared__ float sLw2[64];
    __shared__ float sGw2[64];
    for (int i = threadIdx.x; i < 4096; i += 256) { sLW1[i] = lW1[i]; sGW1[i] = gW1[i]; }
    if (threadIdx.x < 64) { sLw2[threadIdx.x] = lw2[threadIdx.x]; sGw2[threadIdx.x] = gw2[threadIdx.x]; }
    __syncthreads();
    int wave = threadIdx.x >> 6, lane = threadIdx.x & 63;
    int v = blockIdx.x * 4 + wave;
    if (v >= V_NODES) return;
    float nl = lN[v * DD + lane];
    float ng = gN[v * DD + lane];
    float yl = 0.f, yg = 0.f;
#pragma unroll
    for (int k = 0; k < 64; k++) {
        float al = __shfl(nl, k, 64), ag = __shfl(ng, k, 64);
        yl += al * sLW1[k * 64 + lane];
        yg += ag * sGW1[k * 64 + lane];
    }
    float el = waveAllSum(tanhf(yl) * sLw2[lane]);
    float eg = waveAllSum(tanhf(yg) * sGw2[lane]);
    if (lane == 0) { eL[v] = el; eG[v] = eg; }
}

// GAT edge scatter: agg[dst] += exp(e[src]) * N[src], den[dst] += exp(e[src])
__global__ __launch_bounds__(256) void gat_scatter(
    const int* __restrict__ src, const int* __restrict__ dst,
    const float* __restrict__ N, const float* __restrict__ eArr,
    float* __restrict__ agg, float* __restrict__ den, int E)
{
    int gw = (int)((blockIdx.x * 256u + threadIdx.x) >> 6);
    if (gw >= E) return;
    int lane = threadIdx.x & 63;
    int s = src[gw], d = dst[gw];
    float w = __expf(eArr[s]);
    float x = w * N[(long long)s * DD + lane];
    unsafeAtomicAdd(&agg[(long long)d * DD + lane], x);
    if (lane == 0) unsafeAtomicAdd(&den[d], w);
}

// Mean-agg edge scatter: sum[dst] += E_edge, cnt[dst] += 1
__global__ __launch_bounds__(256) void mean_scatter(
    const int* __restrict__ dst, const float* __restrict__ Ebase,
    float* __restrict__ sum, float* __restrict__ cnt, int E)
{
    int gw = (int)((blockIdx.x * 256u + threadIdx.x) >> 6);
    if (gw >= E) return;
    int lane = threadIdx.x & 63;
    int d = dst[gw];
    float x = Ebase[(long long)gw * DD + lane];
    unsafeAtomicAdd(&sum[(long long)d * DD + lane], x);
    if (lane == 0) unsafeAtomicAdd(&cnt[d], 1.0f);
}

// Per-node epilogue: normalize aggregates, 2-way edge attention, project, combine.
__global__ __launch_bounds__(256) void finalize_kernel(
    const float* __restrict__ aggL, const float* __restrict__ denL,
    const float* __restrict__ aggG, const float* __restrict__ denG,
    const float* __restrict__ sumI, const float* __restrict__ cntI,
    const float* __restrict__ sumS, const float* __restrict__ cntS,
    const float* __restrict__ eW1, const float* __restrict__ ew2,
    const float* __restrict__ eW3, const float* __restrict__ Ws,
    float* __restrict__ out)
{
    __shared__ float sW1[4096];
    __shared__ float sW3[4096];
    __shared__ float sw2[64];
    for (int i = threadIdx.x; i < 4096; i += 256) { sW1[i] = eW1[i]; sW3[i] = eW3[i]; }
    if (threadIdx.x < 64) sw2[threadIdx.x] = ew2[threadIdx.x];
    __syncthreads();
    int wave = threadIdx.x >> 6, lane = threadIdx.x & 63;
    int v = blockIdx.x * 4 + wave;
    if (v >= V_NODES) return;

    float dl = denL[v]; dl = dl > 0.f ? dl : 1.f;
    float lNp = aggL[v * DD + lane] / dl;
    float dg = denG[v]; dg = dg > 0.f ? dg : 1.f;
    float Np = aggG[v * DD + lane] / dg;
    float ci = cntI[v]; ci = ci > 0.f ? ci : 1.f;
    float yi = sumI[v * DD + lane] / ci;
    float cs = cntS[v]; cs = cs > 0.f ? cs : 1.f;
    float ys = sumS[v * DD + lane] / cs;

    // tI = (YI @ eW1)[lane], tS = (YS @ eW1)[lane]
    float ti = 0.f, ts = 0.f;
#pragma unroll
    for (int k = 0; k < 64; k++) {
        float w = sW1[k * 64 + lane];
        ti += __shfl(yi, k, 64) * w;
        ts += __shfl(ys, k, 64) * w;
    }
    float eI = waveAllSum(tanhf(ti) * sw2[lane]);
    float eS = waveAllSum(tanhf(ts) * sw2[lane]);
    float m = fmaxf(eI, eS);
    float a0 = __expf(eI - m), a1 = __expf(eS - m);
    float inv = 1.f / (a0 + a1);
    a0 *= inv; a1 *= inv;
    float oy = a0 * yi + a1 * ys;

    // Fg = (OY @ eW3)[lane]
    float fg = 0.f;
#pragma unroll
    for (int k = 0; k < 64; k++) fg += __shfl(oy, k, 64) * sW3[k * 64 + lane];

    float S = Ws[v * DD + lane] * fg + Np;
    out[(long long)v * 128 + lane] = lNp;
    out[(long long)v * 128 + 64 + lane] = S;
}

extern "C" void kernel_launch(void* const* d_in, const int* in_sizes, int n_in,
                              void* d_out, int out_size, void* d_ws, size_t ws_size,
                              hipStream_t stream) {
    const float* local_N = (const float*)d_in[0];
    const float* global_N = (const float*)d_in[1];
    const float* edge_E = (const float*)d_in[2];
    const float* Ws = (const float*)d_in[3];
    const float* lW1 = (const float*)d_in[4];
    const float* lw2 = (const float*)d_in[5];
    const float* gW1 = (const float*)d_in[6];
    const float* gw2 = (const float*)d_in[7];
    const float* eW1 = (const float*)d_in[8];
    const float* ew2 = (const float*)d_in[9];
    const float* eW3 = (const float*)d_in[10];
    const int* ng_src = (const int*)d_in[11];
    const int* ng_dst = (const int*)d_in[12];
    const int* local_src = (const int*)d_in[13];
    const int* local_dst = (const int*)d_in[14];
    const int* int_dst = (const int*)d_in[16];
    const int* sim_dst = (const int*)d_in[18];
    float* out = (float*)d_out;

    const int E_NG = in_sizes[11];
    const int E_LOCAL = in_sizes[13];
    const int E_INT = in_sizes[15];
    const int E_SIM = in_sizes[17];
    const long long V = V_NODES;

    // Workspace layout (fp32)
    float* ws = (float*)d_ws;
    float* eLp = ws;                 // V
    float* eGp = eLp + V;            // V
    float* aggL = eGp + V;           // V*64
    float* denL = aggL + V * 64;     // V
    float* aggG = denL + V;          // V*64
    float* denG = aggG + V * 64;     // V
    float* sumI = denG + V;          // V*64
    float* cntI = sumI + V * 64;     // V
    float* sumS = cntI + V;          // V*64
    float* cntS = sumS + V * 64;     // V

    // Zero all accumulators (everything from aggL onward): V*(4*64+4) floats
    size_t zero_bytes = (size_t)V * (4 * 64 + 4) * sizeof(float);
    hipMemsetAsync(aggL, 0, zero_bytes, stream);

    score_kernel<<<(int)(V / 4), 256, 0, stream>>>(local_N, global_N, lW1, lw2, gW1, gw2, eLp, eGp);

    gat_scatter<<<(E_LOCAL + 3) / 4, 256, 0, stream>>>(local_src, local_dst, local_N, eLp, aggL, denL, E_LOCAL);
    gat_scatter<<<(E_NG + 3) / 4, 256, 0, stream>>>(ng_src, ng_dst, global_N, eGp, aggG, denG, E_NG);
    mean_scatter<<<(E_INT + 3) / 4, 256, 0, stream>>>(int_dst, edge_E, sumI, cntI, E_INT);
    mean_scatter<<<(E_SIM + 3) / 4, 256, 0, stream>>>(sim_dst, edge_E + (long long)E_INT * DD, sumS, cntS, E_SIM);

    finalize_kernel<<<(int)(V / 4), 256, 0, stream>>>(aggL, denL, aggG, denG, sumI, cntI, sumS, cntS,
                                                      eW1, ew2, eW3, Ws, out);
}

// Round 3
// 2118.527 us; speedup vs baseline: 1.1177x; 1.1177x over previous
//
#include <hip/hip_runtime.h>
#include <hip/hip_bf16.h>

#define V_NODES 100000
#define NTOT (4 * V_NODES)      // concatenated per-relation counter space
#define SCAN_CHUNK 4096         // elements per scan block (256 thr x 16)
#define NBLK ((NTOT + SCAN_CHUNK - 1) / SCAN_CHUNK)  // 98

__device__ __forceinline__ float waveAllSum(float v) {
#pragma unroll
    for (int o = 32; o > 0; o >>= 1) v += __shfl_xor(v, o, 64);
    return v;
}

// ---------- per-node attention scores: e = tanh(N @ W1) @ w2 (both GATs) ----------
__global__ __launch_bounds__(256) void score_kernel(
    const float* __restrict__ lN, const float* __restrict__ gN,
    const float* __restrict__ lW1, const float* __restrict__ lw2,
    const float* __restrict__ gW1, const float* __restrict__ gw2,
    float* __restrict__ eL, float* __restrict__ eG)
{
    __shared__ float sLW1[4096];
    __shared__ float sGW1[4096];
    __shared__ float sLw2[64];
    __shared__ float sGw2[64];
    for (int i = threadIdx.x; i < 4096; i += 256) { sLW1[i] = lW1[i]; sGW1[i] = gW1[i]; }
    if (threadIdx.x < 64) { sLw2[threadIdx.x] = lw2[threadIdx.x]; sGw2[threadIdx.x] = gw2[threadIdx.x]; }
    __syncthreads();
    int wave = threadIdx.x >> 6, lane = threadIdx.x & 63;
    int v = blockIdx.x * 4 + wave;
    if (v >= V_NODES) return;
    float nl = lN[v * 64 + lane];
    float ng = gN[v * 64 + lane];
    float yl = 0.f, yg = 0.f;
#pragma unroll
    for (int k = 0; k < 64; k++) {
        float al = __shfl(nl, k, 64), ag = __shfl(ng, k, 64);
        yl += al * sLW1[k * 64 + lane];
        yg += ag * sGW1[k * 64 + lane];
    }
    float el = waveAllSum(tanhf(yl) * sLw2[lane]);
    float eg = waveAllSum(tanhf(yg) * sGw2[lane]);
    if (lane == 0) { eL[v] = el; eG[v] = eg; }
}

// ---------- CSR build ----------
__global__ __launch_bounds__(256) void hist_kernel(const int* __restrict__ dst, int E, int* __restrict__ cnt) {
    int i = blockIdx.x * 256 + threadIdx.x;
    if (i < E) atomicAdd(&cnt[dst[i]], 1);
}

__global__ __launch_bounds__(256) void scan_partial(const int* __restrict__ counts, int* __restrict__ blockSums) {
    __shared__ int sdata[256];
    int base = blockIdx.x * SCAN_CHUNK + threadIdx.x * 16;
    int s = 0;
#pragma unroll
    for (int i = 0; i < 16; i++) { int idx = base + i; if (idx < NTOT) s += counts[idx]; }
    sdata[threadIdx.x] = s;
    __syncthreads();
    for (int o = 128; o > 0; o >>= 1) {
        if (threadIdx.x < o) sdata[threadIdx.x] += sdata[threadIdx.x + o];
        __syncthreads();
    }
    if (threadIdx.x == 0) blockSums[blockIdx.x] = sdata[0];
}

__global__ void scan_blocksums(int* __restrict__ blockSums) {
    __shared__ int s[128];
    int t = threadIdx.x;
    s[t] = (t < NBLK) ? blockSums[t] : 0;
    __syncthreads();
    if (t == 0) {
        int run = 0;
        for (int i = 0; i < NBLK; i++) { int c = s[i]; s[i] = run; run += c; }
    }
    __syncthreads();
    if (t < NBLK) blockSums[t] = s[t];
}

__global__ __launch_bounds__(256) void scan_final(
    const int* __restrict__ counts, const int* __restrict__ blockSums,
    int* __restrict__ off, int* __restrict__ cursor)
{
    __shared__ int pref[256];
    int t = threadIdx.x;
    int base = blockIdx.x * SCAN_CHUNK + t * 16;
    int vals[16];
    int s = 0;
#pragma unroll
    for (int i = 0; i < 16; i++) {
        int idx = base + i;
        int c = (idx < NTOT) ? counts[idx] : 0;
        vals[i] = s; s += c;
    }
    pref[t] = s;
    __syncthreads();
    // Hillis-Steele inclusive scan over 256 thread sums
    for (int o = 1; o < 256; o <<= 1) {
        int v = (t >= o) ? pref[t - o] : 0;
        __syncthreads();
        pref[t] += v;
        __syncthreads();
    }
    int thOff = pref[t] - s + blockSums[blockIdx.x];
#pragma unroll
    for (int i = 0; i < 16; i++) {
        int idx = base + i;
        if (idx < NTOT) { int o2 = thOff + vals[i]; off[idx] = o2; cursor[idx] = o2; }
    }
}

// payload: src id for GAT relations (src != nullptr), else global edge-row id (i + idOffset)
__global__ __launch_bounds__(256) void fill_kernel(
    const int* __restrict__ dst, const int* __restrict__ src, int E,
    int* __restrict__ cursor, int* __restrict__ bucket, int idOffset)
{
    int i = blockIdx.x * 256 + threadIdx.x;
    if (i < E) {
        int d = dst[i];
        int pos = atomicAdd(&cursor[d], 1);
        bucket[pos] = src ? src[i] : (i + idOffset);
    }
}

// ---------- pull aggregations (wave per destination node) ----------
__global__ __launch_bounds__(256) void gat_pull(
    const int* __restrict__ off, const int* __restrict__ endp, const int* __restrict__ bucket,
    const float* __restrict__ N, const float* __restrict__ eArr,
    float* __restrict__ dstBase, int stride)
{
    int wave = threadIdx.x >> 6, lane = threadIdx.x & 63;
    int v = blockIdx.x * 4 + wave;
    if (v >= V_NODES) return;
    int start = off[v], end = endp[v];
    float acc = 0.f, den = 0.f;
    for (int e0 = start; e0 < end; e0 += 64) {
        int n = min(64, end - e0);
        int idx = (lane < n) ? bucket[e0 + lane] : 0;
        float w = (lane < n) ? __expf(eArr[idx]) : 0.f;
        for (int j = 0; j < n; j++) {
            int s = __shfl(idx, j, 64);
            float wj = __shfl(w, j, 64);
            acc += wj * N[(long long)s * 64 + lane];
            den += wj;
        }
    }
    den = den > 0.f ? den : 1.f;
    dstBase[(long long)v * stride + lane] = acc / den;
}

__global__ __launch_bounds__(256) void mean_pull(
    const int* __restrict__ off, const int* __restrict__ endp, const int* __restrict__ bucket,
    const float* __restrict__ Ebase, float* __restrict__ dstBase)
{
    int wave = threadIdx.x >> 6, lane = threadIdx.x & 63;
    int v = blockIdx.x * 4 + wave;
    if (v >= V_NODES) return;
    int start = off[v], end = endp[v];
    float acc = 0.f;
    for (int e0 = start; e0 < end; e0 += 64) {
        int n = min(64, end - e0);
        int idx = (lane < n) ? bucket[e0 + lane] : 0;
        for (int j = 0; j < n; j++) {
            int id = __shfl(idx, j, 64);
            acc += Ebase[(long long)id * 64 + lane];
        }
    }
    float c = (float)(end - start);
    c = c > 0.f ? c : 1.f;
    dstBase[(long long)v * 64 + lane] = acc / c;
}

// ---------- epilogue: 2-way edge attention, project, combine ----------
__global__ __launch_bounds__(256) void finalize_kernel(
    const float* __restrict__ Np, const float* __restrict__ YIb, const float* __restrict__ YSb,
    const float* __restrict__ eW1, const float* __restrict__ ew2,
    const float* __restrict__ eW3, const float* __restrict__ Ws,
    float* __restrict__ out)
{
    __shared__ float sW1[4096];
    __shared__ float sW3[4096];
    __shared__ float sw2[64];
    for (int i = threadIdx.x; i < 4096; i += 256) { sW1[i] = eW1[i]; sW3[i] = eW3[i]; }
    if (threadIdx.x < 64) sw2[threadIdx.x] = ew2[threadIdx.x];
    __syncthreads();
    int wave = threadIdx.x >> 6, lane = threadIdx.x & 63;
    int v = blockIdx.x * 4 + wave;
    if (v >= V_NODES) return;

    float Npv = Np[v * 64 + lane];
    float yi = YIb[v * 64 + lane];
    float ys = YSb[v * 64 + lane];

    float ti = 0.f, ts = 0.f;
#pragma unroll
    for (int k = 0; k < 64; k++) {
        float w = sW1[k * 64 + lane];
        ti += __shfl(yi, k, 64) * w;
        ts += __shfl(ys, k, 64) * w;
    }
    float eI = waveAllSum(tanhf(ti) * sw2[lane]);
    float eS = waveAllSum(tanhf(ts) * sw2[lane]);
    float m = fmaxf(eI, eS);
    float a0 = __expf(eI - m), a1 = __expf(eS - m);
    float inv = 1.f / (a0 + a1);
    a0 *= inv; a1 *= inv;
    float oy = a0 * yi + a1 * ys;

    float fg = 0.f;
#pragma unroll
    for (int k = 0; k < 64; k++) fg += __shfl(oy, k, 64) * sW3[k * 64 + lane];

    float S = Ws[v * 64 + lane] * fg + Npv;
    out[(long long)v * 128 + 64 + lane] = S;
}

extern "C" void kernel_launch(void* const* d_in, const int* in_sizes, int n_in,
                              void* d_out, int out_size, void* d_ws, size_t ws_size,
                              hipStream_t stream) {
    const float* local_N = (const float*)d_in[0];
    const float* global_N = (const float*)d_in[1];
    const float* edge_E = (const float*)d_in[2];
    const float* Ws = (const float*)d_in[3];
    const float* lW1 = (const float*)d_in[4];
    const float* lw2 = (const float*)d_in[5];
    const float* gW1 = (const float*)d_in[6];
    const float* gw2 = (const float*)d_in[7];
    const float* eW1 = (const float*)d_in[8];
    const float* ew2 = (const float*)d_in[9];
    const float* eW3 = (const float*)d_in[10];
    const int* ng_src = (const int*)d_in[11];
    const int* ng_dst = (const int*)d_in[12];
    const int* local_src = (const int*)d_in[13];
    const int* local_dst = (const int*)d_in[14];
    const int* int_dst = (const int*)d_in[16];
    const int* sim_dst = (const int*)d_in[18];
    float* out = (float*)d_out;

    const int E_NG = in_sizes[11];
    const int E_LOCAL = in_sizes[13];
    const int E_INT = in_sizes[15];
    const int E_SIM = in_sizes[17];
    const int E_ALL = E_LOCAL + E_NG + E_INT + E_SIM;
    const long long V = V_NODES;

    // ---- workspace layout ----
    float* fw = (float*)d_ws;
    float* eLp = fw;                 // V
    float* eGp = eLp + V;            // V
    float* Np  = eGp + V;            // V*64
    float* YI  = Np + V * 64;        // V*64
    float* YS  = YI + V * 64;        // V*64
    int* iw = (int*)(YS + V * 64);
    int* counts   = iw;              // NTOT
    int* offsets  = counts + NTOT;   // NTOT
    int* cursor   = offsets + NTOT;  // NTOT
    int* blockSums = cursor + NTOT;  // 128
    int* bucket   = blockSums + 128; // E_ALL

    // relation order in counter space: 0=LOCAL, 1=NG, 2=INT, 3=SIM
    int* cntL = counts + 0 * V_NODES;
    int* cntG = counts + 1 * V_NODES;
    int* cntI = counts + 2 * V_NODES;
    int* cntS = counts + 3 * V_NODES;

    hipMemsetAsync(counts, 0, (size_t)NTOT * sizeof(int), stream);

    score_kernel<<<(int)(V / 4), 256, 0, stream>>>(local_N, global_N, lW1, lw2, gW1, gw2, eLp, eGp);

    hist_kernel<<<(E_LOCAL + 255) / 256, 256, 0, stream>>>(local_dst, E_LOCAL, cntL);
    hist_kernel<<<(E_NG + 255) / 256, 256, 0, stream>>>(ng_dst, E_NG, cntG);
    hist_kernel<<<(E_INT + 255) / 256, 256, 0, stream>>>(int_dst, E_INT, cntI);
    hist_kernel<<<(E_SIM + 255) / 256, 256, 0, stream>>>(sim_dst, E_SIM, cntS);

    scan_partial<<<NBLK, 256, 0, stream>>>(counts, blockSums);
    scan_blocksums<<<1, 128, 0, stream>>>(blockSums);
    scan_final<<<NBLK, 256, 0, stream>>>(counts, blockSums, offsets, cursor);

    fill_kernel<<<(E_LOCAL + 255) / 256, 256, 0, stream>>>(local_dst, local_src, E_LOCAL, cursor + 0 * V_NODES, bucket, 0);
    fill_kernel<<<(E_NG + 255) / 256, 256, 0, stream>>>(ng_dst, ng_src, E_NG, cursor + 1 * V_NODES, bucket, 0);
    fill_kernel<<<(E_INT + 255) / 256, 256, 0, stream>>>(int_dst, nullptr, E_INT, cursor + 2 * V_NODES, bucket, 0);
    fill_kernel<<<(E_SIM + 255) / 256, 256, 0, stream>>>(sim_dst, nullptr, E_SIM, cursor + 3 * V_NODES, bucket, E_INT);

    // pulls: after fill, cursor[rv] == end of node rv's bucket range
    gat_pull<<<(int)(V / 4), 256, 0, stream>>>(offsets + 0 * V_NODES, cursor + 0 * V_NODES, bucket,
                                               local_N, eLp, out, 128);
    gat_pull<<<(int)(V / 4), 256, 0, stream>>>(offsets + 1 * V_NODES, cursor + 1 * V_NODES, bucket,
                                               global_N, eGp, Np, 64);
    mean_pull<<<(int)(V / 4), 256, 0, stream>>>(offsets + 2 * V_NODES, cursor + 2 * V_NODES, bucket,
                                                edge_E, YI);
    mean_pull<<<(int)(V / 4), 256, 0, stream>>>(offsets + 3 * V_NODES, cursor + 3 * V_NODES, bucket,
                                                edge_E, YS);

    finalize_kernel<<<(int)(V / 4), 256, 0, stream>>>(Np, YI, YS, eW1, ew2, eW3, Ws, out);
}